// Round 3
// baseline (104.970 us; speedup 1.0000x reference)
//
#include <hip/hip_runtime.h>

// FerroelectricBasisConv2d on MI355X — round 3.
// Math (verified R1/R2, absmax 0.125): per tuple p=(k,Ec,Ps,b,c):
//   contribution = (Ps*c + b*c) - 2*Ps*c * rcp(exp2(G*sh)+1),  G = 2*log2e*k
//   s = rcp(exp2(CEc + Cx*x)+1),  CEc = -10*log2e*Ec, Cx = -10*log2e
//   G*sh = fma(R, s, fma(G, x, Q)),  Q = 0.8*G*Ec, R = 0.2*G*Ec
//
// R3 structure: 1024 blocks = (b, co, cin-pair). 256 threads, each thread
// evaluates 4 output pixels (4 consecutive rows, same col) -> 4 independent
// dependency chains per thread (ILP to fill the quarter-rate transc pipe)
// and 4x amortization of the uniform LDS param reads. Block transforms its
// own 54 raw tuples inline (no prep kernel) and folds its partial constant
// (+ out_bias on the cinq==0 block) into the atomicAdd epilogue.
// out is zero-inited by an async memset (graph-capturable).

#define LOG2E 1.4426950408889634f

__global__ __launch_bounds__(256, 4) void ferro_main(
    const float* __restrict__ x,
    const float* __restrict__ k, const float* __restrict__ Ec,
    const float* __restrict__ Ps, const float* __restrict__ bias,
    const float* __restrict__ coef, const float* __restrict__ out_bias,
    float* __restrict__ out)
{
    // bid = b*256 + co*8 + cinq   (cinq selects a pair of cin channels)
    const int bid  = blockIdx.x;
    const int cinq = bid & 7;
    const int co   = (bid >> 3) & 31;
    const int b    = bid >> 8;
    const int tid  = threadIdx.x;

    __shared__ float4 p4s[54];          // [cin2][ij][kk]: (CEc, G, Q, R)
    __shared__ float  pAs[54];          // -2*Ps*c
    __shared__ float  xs[2 * 34 * 34];  // padded full image, 2 cins
    __shared__ float  csh;

    // ---- transform this block's 54 raw tuples ----
    float cpart = 0.f;
    if (tid < 54) {
        int pidx = co * 432 + cinq * 54 + tid;   // src order: cin,kk,ij
        float kv = k[pidx];
        float ev = Ec[pidx];
        float pv = Ps[pidx];
        float bv = bias[pidx];
        float cv = coef[pidx];
        float G  = 2.f * LOG2E * kv;
        float4 v;
        v.x = -10.f * LOG2E * ev;  // CEc
        v.y = G;
        v.z = 0.8f * G * ev;       // Q
        v.w = 0.2f * G * ev;       // R
        int cl = tid / 27;
        int r  = tid - cl * 27;
        int kk = r / 9;
        int ij = r - kk * 9;
        int dst = cl * 27 + ij * 3 + kk;         // dst order: cin,ij,kk
        p4s[dst] = v;
        pAs[dst] = -2.f * pv * cv;
        cpart = (pv + bv) * cv;                  // constant part of contribution
    }

    // ---- stage x: 2 cins, full 32x32 image, zero-padded to 34x34 ----
    const int cin0 = cinq * 2;
    const float* xb = x + (b * 16 + cin0) * 1024;
    for (int idx = tid; idx < 2 * 34 * 34; idx += 256) {
        int cin  = idx / 1156;
        int rem  = idx - cin * 1156;
        int row  = rem / 34;
        int colp = rem - row * 34;
        int gr = row - 1;
        int gc = colp - 1;
        float v = 0.f;
        if ((unsigned)gr < 32u && (unsigned)gc < 32u)
            v = xb[(cin * 32 + gr) * 32 + gc];
        xs[idx] = v;
    }

    // ---- reduce this block's constant (all 54 contributors are in wave 0) ----
    if (tid < 64) {
        #pragma unroll
        for (int off = 32; off > 0; off >>= 1)
            cpart += __shfl_down(cpart, off, 64);
        if (tid == 0) csh = cpart;
    }
    __syncthreads();

    // ---- eval: 4 pixels/thread (rows row0..row0+3, same col) ----
    const int col  = tid & 31;
    const int row0 = (tid >> 5) * 4;
    const float Cx = -10.f * LOG2E;
    float acc[4] = {0.f, 0.f, 0.f, 0.f};

    #pragma unroll 1
    for (int cin = 0; cin < 2; ++cin) {
        const float*  xc = &xs[cin * 1156];
        const float4* pp = &p4s[cin * 27];
        const float*  aa = &pAs[cin * 27];
        #pragma unroll
        for (int ij = 0; ij < 9; ++ij) {
            const int i = ij / 3, j = ij - (ij / 3) * 3;
            float xv[4], xC[4];
            #pragma unroll
            for (int p = 0; p < 4; ++p) {
                xv[p] = xc[(row0 + p + i) * 34 + (col + j)];
                xC[p] = Cx * xv[p];
            }
            #pragma unroll
            for (int kk = 0; kk < 3; ++kk) {
                float4 v  = pp[ij * 3 + kk];
                float  a2 = aa[ij * 3 + kk];
                #pragma unroll
                for (int p = 0; p < 4; ++p) {
                    float e1 = __builtin_amdgcn_exp2f(xC[p] + v.x);
                    float s  = __builtin_amdgcn_rcpf(e1 + 1.f);
                    float arg2 = fmaf(v.w, s, fmaf(v.y, xv[p], v.z));
                    float e2 = __builtin_amdgcn_exp2f(arg2);
                    float u  = __builtin_amdgcn_rcpf(e2 + 1.f);
                    acc[p] = fmaf(a2, u, acc[p]);
                }
            }
        }
    }

    // ---- epilogue: fold block constant (+ out_bias once) into atomics ----
    float val = csh + ((cinq == 0) ? out_bias[co] : 0.f);
    float* op = &out[((b * 32 + co) * 32 + row0) * 32 + col];
    #pragma unroll
    for (int p = 0; p < 4; ++p)
        atomicAdd(op + p * 32, acc[p] + val);
}

extern "C" void kernel_launch(void* const* d_in, const int* in_sizes, int n_in,
                              void* d_out, int out_size, void* d_ws, size_t ws_size,
                              hipStream_t stream) {
    const float* x        = (const float*)d_in[0];
    const float* k        = (const float*)d_in[1];
    const float* Ec       = (const float*)d_in[2];
    const float* Ps       = (const float*)d_in[3];
    const float* bias     = (const float*)d_in[4];
    const float* coef     = (const float*)d_in[5];
    const float* out_bias = (const float*)d_in[6];
    float* out = (float*)d_out;

    hipMemsetAsync(out, 0, (size_t)out_size * sizeof(float), stream);
    ferro_main<<<dim3(1024), dim3(256), 0, stream>>>(
        x, k, Ec, Ps, bias, coef, out_bias, out);
}

// Round 4
// 91.640 us; speedup vs baseline: 1.1455x; 1.1455x over previous
//
#include <hip/hip_runtime.h>

// FerroelectricBasisConv2d on MI355X — round 4.
// Math (verified R1-R3): per tuple p=(k,Ec,Ps,b,c):
//   contribution = (Ps*c + b*c) - 2*Ps*c * rcp(exp2(G*sh)+1),  G = 2*log2e*k
//   s = rcp(exp2(CEc + Cx*x)+1),  CEc = -10*log2e*Ec, Cx = -10*log2e
//   G*sh = fma(R, s, fma(G, x, Q)),  Q = 0.8*G*Ec, R = 0.2*G*Ec
//
// R4: NO atomics (R3's 81 MB atomic write amplification was the bottleneck).
// 1024 blocks (4/CU) x 256 threads. Block = (b, co, 4-row strip); wave w owns
// row r0+w. Lanes: col = lane&31, cinh = lane>>5 -> each lane reduces
// 8 cins x 27 tuples for one pixel; halves combine via __shfl_xor(32);
// lane<32 stores once. Per-cout constant + out_bias folded into the store.

#define LOG2E 1.4426950408889634f

__global__ __launch_bounds__(256, 4) void ferro_main(
    const float* __restrict__ x,
    const float* __restrict__ k, const float* __restrict__ Ec,
    const float* __restrict__ Ps, const float* __restrict__ bias,
    const float* __restrict__ coef, const float* __restrict__ out_bias,
    float* __restrict__ out)
{
    // bid = b*256 + co*8 + rs
    const int bid = blockIdx.x;
    const int rs  = bid & 7;          // 8 row-strips of 4 rows
    const int co  = (bid >> 3) & 31;
    const int b   = bid >> 8;
    const int tid = threadIdx.x;

    __shared__ float4 p4s[432];          // [cin16][ij9][kk3]: (CEc, G, Q, R)
    __shared__ float  pAs[432];          // -2*Ps*c
    __shared__ float  xs[16 * 6 * 34];   // [cin16][row6][col34], rows r0-1..r0+4
    __shared__ float  red[4];
    __shared__ float  csh;

    // ---- transform all 432 raw tuples for this co ----
    const int pbase = co * 432;
    float cpart = 0.f;
    for (int s = tid; s < 432; s += 256) {
        float kv = k[pbase + s];
        float ev = Ec[pbase + s];
        float pv = Ps[pbase + s];
        float bv = bias[pbase + s];
        float cv = coef[pbase + s];
        float G  = 2.f * LOG2E * kv;
        float4 v;
        v.x = -10.f * LOG2E * ev;  // CEc
        v.y = G;
        v.z = 0.8f * G * ev;       // Q
        v.w = 0.2f * G * ev;       // R
        // src s = cin*27 + kk*9 + ij  ->  dst = cin*27 + ij*3 + kk
        int cin = s / 27;
        int r   = s - cin * 27;
        int kk  = r / 9;
        int ij  = r - kk * 9;
        int dst = cin * 27 + ij * 3 + kk;
        p4s[dst] = v;
        pAs[dst] = -2.f * pv * cv;
        cpart += (pv + bv) * cv;
    }

    // ---- stage x: 16 cins, rows r0-1..r0+4, cols -1..32 (zero pad) ----
    const int r0 = rs * 4;
    const float* xb = x + b * (16 * 1024);
    for (int idx = tid; idx < 16 * 204; idx += 256) {
        int cin  = idx / 204;
        int rem  = idx - cin * 204;
        int row6 = rem / 34;
        int colp = rem - row6 * 34;
        int gr = r0 + row6 - 1;
        int gc = colp - 1;
        float v = 0.f;
        if ((unsigned)gr < 32u && (unsigned)gc < 32u)
            v = xb[(cin * 32 + gr) * 32 + gc];
        xs[idx] = v;
    }

    // ---- reduce per-cout constant across the block ----
    #pragma unroll
    for (int off = 32; off > 0; off >>= 1)
        cpart += __shfl_down(cpart, off, 64);
    if ((tid & 63) == 0) red[tid >> 6] = cpart;
    __syncthreads();
    if (tid == 0) csh = red[0] + red[1] + red[2] + red[3];
    __syncthreads();

    // ---- eval: wave w -> row r0+w; lane = col(32) x cinh(2); 216 evals/lane
    const int lane = tid & 63;
    const int w    = tid >> 6;
    const int col  = lane & 31;
    const int cinh = lane >> 5;
    const float Cx = -10.f * LOG2E;
    float acc0 = 0.f, acc1 = 0.f, acc2 = 0.f;

    #pragma unroll 1
    for (int c8 = 0; c8 < 8; ++c8) {
        const int cin = cinh * 8 + c8;
        const float*  xr = &xs[cin * 204 + w * 34 + col];  // xr[i*34+j]
        const float4* pp = &p4s[cin * 27];
        const float*  aa = &pAs[cin * 27];
        #pragma unroll
        for (int ij = 0; ij < 9; ++ij) {
            const int i = ij / 3, j = ij - (ij / 3) * 3;
            float xv = xr[i * 34 + j];
            float xC = Cx * xv;
            {
                float4 v  = pp[ij * 3 + 0];
                float e1 = __builtin_amdgcn_exp2f(xC + v.x);
                float s  = __builtin_amdgcn_rcpf(e1 + 1.f);
                float e2 = __builtin_amdgcn_exp2f(fmaf(v.w, s, fmaf(v.y, xv, v.z)));
                float u  = __builtin_amdgcn_rcpf(e2 + 1.f);
                acc0 = fmaf(aa[ij * 3 + 0], u, acc0);
            }
            {
                float4 v  = pp[ij * 3 + 1];
                float e1 = __builtin_amdgcn_exp2f(xC + v.x);
                float s  = __builtin_amdgcn_rcpf(e1 + 1.f);
                float e2 = __builtin_amdgcn_exp2f(fmaf(v.w, s, fmaf(v.y, xv, v.z)));
                float u  = __builtin_amdgcn_rcpf(e2 + 1.f);
                acc1 = fmaf(aa[ij * 3 + 1], u, acc1);
            }
            {
                float4 v  = pp[ij * 3 + 2];
                float e1 = __builtin_amdgcn_exp2f(xC + v.x);
                float s  = __builtin_amdgcn_rcpf(e1 + 1.f);
                float e2 = __builtin_amdgcn_exp2f(fmaf(v.w, s, fmaf(v.y, xv, v.z)));
                float u  = __builtin_amdgcn_rcpf(e2 + 1.f);
                acc2 = fmaf(aa[ij * 3 + 2], u, acc2);
            }
        }
    }

    float acc = (acc0 + acc1) + acc2;
    acc += __shfl_xor(acc, 32, 64);
    if (cinh == 0) {
        out[((b * 32 + co) * 32 + (r0 + w)) * 32 + col] = acc + csh + out_bias[co];
    }
}

extern "C" void kernel_launch(void* const* d_in, const int* in_sizes, int n_in,
                              void* d_out, int out_size, void* d_ws, size_t ws_size,
                              hipStream_t stream) {
    const float* x        = (const float*)d_in[0];
    const float* k        = (const float*)d_in[1];
    const float* Ec       = (const float*)d_in[2];
    const float* Ps       = (const float*)d_in[3];
    const float* bias     = (const float*)d_in[4];
    const float* coef     = (const float*)d_in[5];
    const float* out_bias = (const float*)d_in[6];
    float* out = (float*)d_out;

    ferro_main<<<dim3(1024), dim3(256), 0, stream>>>(
        x, k, Ec, Ps, bias, coef, out_bias, out);
}

// Round 5
// 91.176 us; speedup vs baseline: 1.1513x; 1.0051x over previous
//
#include <hip/hip_runtime.h>

// FerroelectricBasisConv2d on MI355X — round 5.
// Math (verified R1-R4): per tuple p=(k,Ec,Ps,b,c):
//   s   = rcp(exp2(CEc + Cx*x) + 1),   CEc = -10*log2e*Ec, Cx = -10*log2e
//   sh  = fma(Q', fma(0.25, s, 1.0), x),  Q' = 0.8*Ec   (0.2*Ec == 0.25*Q')
//   u   = rcp(exp2(G*sh) + 1),            G  = 2*log2e*k
//   contribution = (Ps*c + b*c) + A*u,    A  = -2*Ps*c
// -> per-tuple params fit ONE float4 (CEc, G, Q', A): single ds_read_b128/eval.
//
// R5 structure: 2048 blocks = (b4, co32, 2-row strip16), 256 threads,
// __launch_bounds__(256,8) -> VGPR<=64, ~16KB LDS -> 8 blocks/CU (8 waves/SIMD)
// to hide LDS latency. Wave w: row=w>>1, cin-octet=w&1. Lane: col(32) x
// cin-quartet(2) -> 4 cins x 27 tuples per lane, 3 independent acc chains.
// Reduction: shfl_xor(32) + LDS partials; each pixel stored exactly once.

#define LOG2E 1.4426950408889634f

__global__ __launch_bounds__(256, 8) void ferro_main(
    const float* __restrict__ x,
    const float* __restrict__ k, const float* __restrict__ Ec,
    const float* __restrict__ Ps, const float* __restrict__ bias,
    const float* __restrict__ coef, const float* __restrict__ out_bias,
    float* __restrict__ out)
{
    // bid = b*512 + co*16 + rs
    const int bid = blockIdx.x;
    const int rs  = bid & 15;         // 16 row-pairs
    const int co  = (bid >> 4) & 31;
    const int b   = bid >> 9;
    const int tid = threadIdx.x;

    __shared__ float4 p4s[432];        // [cin16][ij9][kk3]: (CEc, G, Q', A)
    __shared__ float  xs[16 * 4 * 34]; // [cin16][row4][col34], rows r0-1..r0+2
    __shared__ float  red[128];        // [wave4][col32] partials
    __shared__ float  redc[4];
    __shared__ float  csh;

    // ---- transform all 432 raw tuples for this co (one float4 each) ----
    const int pbase = co * 432;
    float cpart = 0.f;
    for (int s = tid; s < 432; s += 256) {
        float kv = k[pbase + s];
        float ev = Ec[pbase + s];
        float pv = Ps[pbase + s];
        float bv = bias[pbase + s];
        float cv = coef[pbase + s];
        float4 v;
        v.x = -10.f * LOG2E * ev;   // CEc
        v.y = 2.f * LOG2E * kv;     // G
        v.z = 0.8f * ev;            // Q'
        v.w = -2.f * pv * cv;       // A
        // src s = cin*27 + kk*9 + ij  ->  dst = cin*27 + ij*3 + kk
        int cin = s / 27;
        int r   = s - cin * 27;
        int kk  = r / 9;
        int ij  = r - kk * 9;
        p4s[cin * 27 + ij * 3 + kk] = v;
        cpart += (pv + bv) * cv;
    }

    // ---- stage x: 16 cins, rows r0-1..r0+2, cols -1..32 (zero pad) ----
    const int r0 = rs * 2;
    const float* xb = x + b * (16 * 1024);
    for (int idx = tid; idx < 16 * 136; idx += 256) {
        int cin  = idx / 136;
        int rem  = idx - cin * 136;
        int row4 = rem / 34;
        int colp = rem - row4 * 34;
        int gr = r0 + row4 - 1;
        int gc = colp - 1;
        float v = 0.f;
        if ((unsigned)gr < 32u && (unsigned)gc < 32u)
            v = xb[(cin * 32 + gr) * 32 + gc];
        xs[idx] = v;
    }

    // ---- reduce per-cout constant ----
    #pragma unroll
    for (int off = 32; off > 0; off >>= 1)
        cpart += __shfl_down(cpart, off, 64);
    if ((tid & 63) == 0) redc[tid >> 6] = cpart;
    __syncthreads();
    if (tid == 0) csh = redc[0] + redc[1] + redc[2] + redc[3];
    __syncthreads();

    // ---- eval: wave w -> (row = w>>1, cin-octet = w&1); lane -> col x cinh
    const int lane = tid & 63;
    const int w    = tid >> 6;
    const int row  = w >> 1;          // 0..1 -> output row r0+row
    const int cinq = w & 1;
    const int col  = lane & 31;
    const int cinh = lane >> 5;
    const float Cx = -10.f * LOG2E;
    float acc0 = 0.f, acc1 = 0.f, acc2 = 0.f;

    const int cinbase = cinq * 8 + cinh * 4;
    #pragma unroll 1
    for (int c = 0; c < 4; ++c) {
        const int cin = cinbase + c;
        const float*  xr = &xs[cin * 136 + row * 34 + col];  // xr[i*34+j]
        const float4* pp = &p4s[cin * 27];
        #pragma unroll
        for (int ij = 0; ij < 9; ++ij) {
            const int i = ij / 3, j = ij - (ij / 3) * 3;
            float xv = xr[i * 34 + j];
            float xC = Cx * xv;
            {
                float4 v = pp[ij * 3 + 0];
                float e1 = __builtin_amdgcn_exp2f(xC + v.x);
                float s  = __builtin_amdgcn_rcpf(e1 + 1.f);
                float sh = fmaf(v.z, fmaf(0.25f, s, 1.f), xv);
                float e2 = __builtin_amdgcn_exp2f(v.y * sh);
                float u  = __builtin_amdgcn_rcpf(e2 + 1.f);
                acc0 = fmaf(v.w, u, acc0);
            }
            {
                float4 v = pp[ij * 3 + 1];
                float e1 = __builtin_amdgcn_exp2f(xC + v.x);
                float s  = __builtin_amdgcn_rcpf(e1 + 1.f);
                float sh = fmaf(v.z, fmaf(0.25f, s, 1.f), xv);
                float e2 = __builtin_amdgcn_exp2f(v.y * sh);
                float u  = __builtin_amdgcn_rcpf(e2 + 1.f);
                acc1 = fmaf(v.w, u, acc1);
            }
            {
                float4 v = pp[ij * 3 + 2];
                float e1 = __builtin_amdgcn_exp2f(xC + v.x);
                float s  = __builtin_amdgcn_rcpf(e1 + 1.f);
                float sh = fmaf(v.z, fmaf(0.25f, s, 1.f), xv);
                float e2 = __builtin_amdgcn_exp2f(v.y * sh);
                float u  = __builtin_amdgcn_rcpf(e2 + 1.f);
                acc2 = fmaf(v.w, u, acc2);
            }
        }
    }

    float acc = (acc0 + acc1) + acc2;
    acc += __shfl_xor(acc, 32, 64);      // combine cinh halves
    if (cinh == 0) red[w * 32 + col] = acc;
    __syncthreads();

    // ---- final: combine cin-octet wave pairs, add constant, store once ----
    if (tid < 64) {
        int r   = tid >> 5;
        int cl  = tid & 31;
        float v = red[(r * 2 + 0) * 32 + cl] + red[(r * 2 + 1) * 32 + cl]
                + csh + out_bias[co];
        out[((b * 32 + co) * 32 + (r0 + r)) * 32 + cl] = v;
    }
}

extern "C" void kernel_launch(void* const* d_in, const int* in_sizes, int n_in,
                              void* d_out, int out_size, void* d_ws, size_t ws_size,
                              hipStream_t stream) {
    const float* x        = (const float*)d_in[0];
    const float* k        = (const float*)d_in[1];
    const float* Ec       = (const float*)d_in[2];
    const float* Ps       = (const float*)d_in[3];
    const float* bias     = (const float*)d_in[4];
    const float* coef     = (const float*)d_in[5];
    const float* out_bias = (const float*)d_in[6];
    float* out = (float*)d_out;

    ferro_main<<<dim3(2048), dim3(256), 0, stream>>>(
        x, k, Ec, Ps, bias, coef, out_bias, out);
}